// Round 1
// baseline (285.582 us; speedup 1.0000x reference)
//
#include <hip/hip_runtime.h>

#define KTAGS 32
#define BOSI 30
#define EOSI 31

// XOR-swizzle within 32-lane groups: lane j reads lane j^PAT (BitMode offset)
template<int PAT>
__device__ __forceinline__ float swz_xor(float v) {
    return __int_as_float(__builtin_amdgcn_ds_swizzle(__float_as_int(v), (PAT << 10) | 0x1F));
}
// broadcast group-local lane 0 (and=0, or=0, xor=0)
__device__ __forceinline__ float bcast0(float v) {
    return __int_as_float(__builtin_amdgcn_ds_swizzle(__float_as_int(v), 0x0000));
}

// unrolled matvec accumulation: acc[k&3] += u[tag^k] * Ep[k], k = 1..31
template<int K>
struct MV {
    static __device__ __forceinline__ void run(float u, const float (&Ep)[32], float (&acc)[4]) {
        acc[K & 3] = fmaf(swz_xor<K>(u), Ep[K], acc[K & 3]);
        MV<K + 1>::run(u, Ep, acc);
    }
};
template<>
struct MV<32> {
    static __device__ __forceinline__ void run(float, const float (&)[32], float (&)[4]) {}
};

__global__ __launch_bounds__(256) void crf_fwd_kernel(const float* __restrict__ em,
                                                      const float* __restrict__ tr,
                                                      float* __restrict__ out,
                                                      int T) {
    __shared__ float E[KTAGS * KTAGS];  // exp(transitions)
    const int tid = threadIdx.x;

    // build exp(transitions) table (1024 entries, 256 threads)
#pragma unroll
    for (int k = 0; k < 4; ++k) {
        int idx = tid + k * 256;
        E[idx] = __expf(tr[idx]);
    }
    __syncthreads();

    const int tag = tid & 31;
    const int b = blockIdx.x * 8 + (tid >> 5);  // 8 sequences per block

    // per-lane permuted row of exp(T): Ep[k] = exp(T[tag, tag^k])
    float Ep[32];
#pragma unroll
    for (int k = 0; k < 32; ++k) Ep[k] = E[tag * 32 + (tag ^ k)];

    const float tEOS = tr[EOSI * 32 + tag];  // transitions[EOS, tag]

    const float* eptr = em + (size_t)b * T * KTAGS + tag;

    // alpha after "virtual step -1": BOS=0, rest = NEG_INIT
    float alpha = (tag == BOSI) ? 0.f : -10000.f;
    // shift pipeline: m_use valid for current step; stale-by-2 in steady state
    float m_use = 0.f, m_next = 0.f;

    float ecur[8], enx[8];
#pragma unroll
    for (int q = 0; q < 8; ++q) ecur[q] = eptr[q * 32];

    const int NC = T / 8;  // 64 chunks of 8 steps
    for (int c = 0; c < NC; ++c) {
        const int cn = (c + 1 < NC) ? (c + 1) : c;  // clamp: redundant last prefetch
#pragma unroll
        for (int q = 0; q < 8; ++q) enx[q] = eptr[(size_t)cn * 256 + q * 32];

#pragma unroll
        for (int q = 0; q < 8; ++q) {
            float u = __expf(alpha - m_use);
            float acc[4];
            acc[0] = u * Ep[0];
            acc[1] = 0.f;
            acc[2] = 0.f;
            acc[3] = 0.f;
            MV<1>::run(u, Ep, acc);
            float y = (acc[0] + acc[1]) + (acc[2] + acc[3]);
            alpha = ecur[q] + m_use + __logf(y);
            float mq = bcast0(alpha);  // broadcast alpha[tag 0], used 2 steps later
            m_use = m_next;
            m_next = mq;
        }
#pragma unroll
        for (int q = 0; q < 8; ++q) ecur[q] = enx[q];
    }

    // terminal: logsumexp_j(alpha[j] + T[EOS, j]) over the 32-lane group
    float t = alpha + tEOS;
    float mx = t;
    mx = fmaxf(mx, swz_xor<1>(mx));
    mx = fmaxf(mx, swz_xor<2>(mx));
    mx = fmaxf(mx, swz_xor<4>(mx));
    mx = fmaxf(mx, swz_xor<8>(mx));
    mx = fmaxf(mx, swz_xor<16>(mx));
    float s = __expf(t - mx);
    s += swz_xor<1>(s);
    s += swz_xor<2>(s);
    s += swz_xor<4>(s);
    s += swz_xor<8>(s);
    s += swz_xor<16>(s);
    float res = mx + __logf(s);
    if (tag == 0) out[b] = res;
}

extern "C" void kernel_launch(void* const* d_in, const int* in_sizes, int n_in,
                              void* d_out, int out_size, void* d_ws, size_t ws_size,
                              hipStream_t stream) {
    const float* em = (const float*)d_in[0];
    const float* tr = (const float*)d_in[1];
    float* out = (float*)d_out;

    const int T = 512;
    const int B = in_sizes[0] / (T * KTAGS);  // 2048
    const int blocks = B / 8;                 // 256 blocks x 256 threads (8 seqs/block)

    crf_fwd_kernel<<<blocks, 256, 0, stream>>>(em, tr, out, T);
}